// Round 1
// baseline (9135.792 us; speedup 1.0000x reference)
//
#include <hip/hip_runtime.h>
#include <hip/hip_bf16.h>

// MLA fp32 baseline. B=2, S=2048, E=2048, C=512, H=16, Dn=128, Dr=64.
// Workspace layout (floats): y_q[4096*512] y_kv[4096*512] q[4096*3072]
// kn[4096*2048] v[4096*2048] kr[4096*64] ao[4096*2048]  => ~169 MB total.

#define S_ 2048
#define H_ 16

// ---------------- generic fp32 GEMM: C = A(MxK) @ B(KxN), row-major ----------
__global__ __launch_bounds__(256) void gemm_f32(
    const float* __restrict__ A, const float* __restrict__ Bm,
    float* __restrict__ C, int M, int N, int K) {
  const int BK = 16;
  __shared__ float As[16][65];
  __shared__ float Bs[16][65];
  int tid = threadIdx.x;
  int bm = blockIdx.y * 64, bn = blockIdx.x * 64;
  int tcol = tid & 15, trow = tid >> 4;
  float acc[4][4] = {};
  for (int k0 = 0; k0 < K; k0 += BK) {
    // A tile: 64 rows x 16 k; consecutive tid -> consecutive k
#pragma unroll
    for (int i = 0; i < 4; i++) {
      int r = (tid >> 4) + i * 16, c = tid & 15;
      As[c][r] = A[(size_t)(bm + r) * K + k0 + c];
    }
    // B tile: 16 k x 64 n; consecutive tid -> consecutive n
#pragma unroll
    for (int i = 0; i < 4; i++) {
      int r = (tid >> 6) + i * 4, c = tid & 63;
      Bs[r][c] = Bm[(size_t)(k0 + r) * N + bn + c];
    }
    __syncthreads();
#pragma unroll
    for (int kk = 0; kk < BK; kk++) {
      float a[4], b[4];
#pragma unroll
      for (int i = 0; i < 4; i++) a[i] = As[kk][trow * 4 + i];
#pragma unroll
      for (int j = 0; j < 4; j++) b[j] = Bs[kk][tcol * 4 + j];
#pragma unroll
      for (int i = 0; i < 4; i++)
#pragma unroll
        for (int j = 0; j < 4; j++) acc[i][j] = fmaf(a[i], b[j], acc[i][j]);
    }
    __syncthreads();
  }
#pragma unroll
  for (int i = 0; i < 4; i++)
#pragma unroll
    for (int j = 0; j < 4; j++)
      C[(size_t)(bm + trow * 4 + i) * N + bn + tcol * 4 + j] = acc[i][j];
}

// ---------------- rmsnorm over rows of length 512, in place ------------------
__global__ __launch_bounds__(256) void rmsnorm512(float* __restrict__ x,
                                                  const float* __restrict__ g) {
  int row = blockIdx.x;
  float* p = x + (size_t)row * 512;
  int t = threadIdx.x;
  float v0 = p[t], v1 = p[t + 256];
  __shared__ float red[256];
  red[t] = v0 * v0 + v1 * v1;
  __syncthreads();
  for (int s = 128; s > 0; s >>= 1) {
    if (t < s) red[t] += red[t + s];
    __syncthreads();
  }
  float r = rsqrtf(red[0] / 512.f + 1e-6f);
  p[t] = v0 * r * g[t];
  p[t + 256] = v1 * r * g[t + 256];
}

// ---------------- rope on rows x 64 (position = row % S_), in place ----------
__global__ void rope64(float* __restrict__ x, int rows) {
  int i = blockIdx.x * blockDim.x + threadIdx.x;
  if (i >= rows * 32) return;
  int r = i >> 5, j = i & 31;
  int s = r & (S_ - 1);
  float freq = powf(10000.f, -(float)(2 * j) / 64.f);
  float ang = (float)s * freq;
  float c = cosf(ang), sn = sinf(ang);
  size_t base = (size_t)r * 64 + 2 * j;
  float x0 = x[base], x1 = x[base + 1];
  x[base] = x0 * c - x1 * sn;
  x[base + 1] = x1 * c + x0 * sn;
}

// ------------- rope on q rope-section: q is 4096 x 3072, cols h*192+128.. ----
__global__ void rope_q(float* __restrict__ q) {
  int i = blockIdx.x * blockDim.x + threadIdx.x;  // 4096*16*32 pairs
  int j = i & 31;
  int h = (i >> 5) & 15;
  int r = i >> 9;
  if (r >= 4096) return;
  int s = r & (S_ - 1);
  float freq = powf(10000.f, -(float)(2 * j) / 64.f);
  float ang = (float)s * freq;
  float c = cosf(ang), sn = sinf(ang);
  size_t base = (size_t)r * 3072 + h * 192 + 128 + 2 * j;
  float x0 = q[base], x1 = q[base + 1];
  q[base] = x0 * c - x1 * sn;
  q[base + 1] = x1 * c + x0 * sn;
}

// ---------------- attention: one block per (b,h,s) query row -----------------
__global__ __launch_bounds__(256) void attn_row(
    const float* __restrict__ q,   // 4096 x 3072
    const float* __restrict__ kn,  // 4096 x 2048
    const float* __restrict__ kr,  // 4096 x 64
    const float* __restrict__ v,   // 4096 x 2048
    float* __restrict__ o) {       // 4096 x 2048
  int bid = blockIdx.x;
  int s = bid & (S_ - 1);
  int h = (bid >> 11) & (H_ - 1);
  int b = bid >> 15;
  int t = threadIdx.x;
  __shared__ float qs[192];
  __shared__ float sc[S_];
  __shared__ float red[256];
  const float* qrow = q + (size_t)(b * S_ + s) * 3072 + h * 192;
  if (t < 192) qs[t] = qrow[t];
  __syncthreads();
  int nk = s + 1;
  const float scale = 0.07216878364870323f;  // 1/sqrt(192)
  const float* knb = kn + (size_t)b * S_ * 2048 + h * 128;
  const float* krb = kr + (size_t)b * S_ * 64;
  for (int j = t; j < nk; j += 256) {
    const float* kj = knb + (size_t)j * 2048;
    const float* rj = krb + (size_t)j * 64;
    float d = 0.f;
#pragma unroll 8
    for (int d0 = 0; d0 < 128; d0++) d = fmaf(qs[d0], kj[d0], d);
#pragma unroll 8
    for (int d0 = 0; d0 < 64; d0++) d = fmaf(qs[128 + d0], rj[d0], d);
    sc[j] = d * scale;
  }
  __syncthreads();
  // block max
  float m = -1e30f;
  for (int j = t; j < nk; j += 256) m = fmaxf(m, sc[j]);
  red[t] = m;
  __syncthreads();
  for (int w = 128; w > 0; w >>= 1) {
    if (t < w) red[t] = fmaxf(red[t], red[t + w]);
    __syncthreads();
  }
  m = red[0];
  __syncthreads();
  // exp + sum
  float sum = 0.f;
  for (int j = t; j < nk; j += 256) {
    float e = expf(sc[j] - m);
    sc[j] = e;
    sum += e;
  }
  red[t] = sum;
  __syncthreads();
  for (int w = 128; w > 0; w >>= 1) {
    if (t < w) red[t] += red[t + w];
    __syncthreads();
  }
  float inv = 1.f / red[0];
  // weighted V accumulate
  const float* vb = v + (size_t)b * S_ * 2048 + h * 128;
  if (t < 128) {
    float acc = 0.f;
    for (int j = 0; j < nk; j++) acc = fmaf(sc[j], vb[(size_t)j * 2048 + t], acc);
    o[(size_t)(b * S_ + s) * 2048 + h * 128 + t] = acc * inv;
  }
}

extern "C" void kernel_launch(void* const* d_in, const int* in_sizes, int n_in,
                              void* d_out, int out_size, void* d_ws, size_t ws_size,
                              hipStream_t stream) {
  const float* x        = (const float*)d_in[0];  // (2,2048,2048)
  const float* w_dq     = (const float*)d_in[1];  // (2048,512)
  const float* g_q      = (const float*)d_in[2];  // (512,)
  const float* w_uq     = (const float*)d_in[3];  // (512,3072)
  const float* w_dkv    = (const float*)d_in[4];  // (2048,512)
  const float* g_kv     = (const float*)d_in[5];  // (512,)
  const float* w_ukrope = (const float*)d_in[6];  // (2048,64)
  const float* w_uv     = (const float*)d_in[7];  // (512,2048)
  const float* w_uknope = (const float*)d_in[8];  // (512,2048)
  const float* w_o      = (const float*)d_in[9];  // (2048,2048)
  float* out = (float*)d_out;

  const int M = 4096;
  float* ws = (float*)d_ws;
  float* y_q  = ws;                    // 4096*512
  float* y_kv = y_q + (size_t)M * 512; // 4096*512
  float* q    = y_kv + (size_t)M * 512;   // 4096*3072
  float* kn   = q + (size_t)M * 3072;     // 4096*2048
  float* v    = kn + (size_t)M * 2048;    // 4096*2048
  float* kr   = v + (size_t)M * 2048;     // 4096*64
  float* ao   = kr + (size_t)M * 64;      // 4096*2048

  dim3 blk(256);
  // down-projections + rope base
  gemm_f32<<<dim3(512 / 64, M / 64), blk, 0, stream>>>(x, w_dq, y_q, M, 512, 2048);
  gemm_f32<<<dim3(512 / 64, M / 64), blk, 0, stream>>>(x, w_dkv, y_kv, M, 512, 2048);
  gemm_f32<<<dim3(64 / 64, M / 64), blk, 0, stream>>>(x, w_ukrope, kr, M, 64, 2048);
  // rmsnorms (in place)
  rmsnorm512<<<M, blk, 0, stream>>>(y_q, g_q);
  rmsnorm512<<<M, blk, 0, stream>>>(y_kv, g_kv);
  // up-projections
  gemm_f32<<<dim3(3072 / 64, M / 64), blk, 0, stream>>>(y_q, w_uq, q, M, 3072, 512);
  gemm_f32<<<dim3(2048 / 64, M / 64), blk, 0, stream>>>(y_kv, w_uknope, kn, M, 2048, 512);
  gemm_f32<<<dim3(2048 / 64, M / 64), blk, 0, stream>>>(y_kv, w_uv, v, M, 2048, 512);
  // rope (in place)
  rope64<<<(M * 32 + 255) / 256, blk, 0, stream>>>(kr, M);
  rope_q<<<(M * 16 * 32 + 255) / 256, blk, 0, stream>>>(q);
  // attention
  attn_row<<<2 * H_ * S_, blk, 0, stream>>>(q, kn, kr, v, ao);
  // output projection
  gemm_f32<<<dim3(2048 / 64, M / 64), blk, 0, stream>>>(ao, w_o, out, M, 2048, 2048);
}

// Round 2
// 2567.403 us; speedup vs baseline: 3.5584x; 3.5584x over previous
//
#include <hip/hip_runtime.h>
#include <hip/hip_bf16.h>

// MLA: fp32 GEMMs + bf16 MFMA flash attention.
// B=2, S=2048, E=2048, C=512, H=16, Dn=128, Dr=64.

#define S_ 2048
#define H_ 16

typedef __bf16 bf16_t;
typedef __bf16 bf16x8 __attribute__((ext_vector_type(8)));
typedef float f32x4 __attribute__((ext_vector_type(4)));

// ---------------- generic fp32 GEMM: C = A(MxK) @ B(KxN), row-major ----------
__global__ __launch_bounds__(256) void gemm_f32(
    const float* __restrict__ A, const float* __restrict__ Bm,
    float* __restrict__ C, int M, int N, int K) {
  const int BK = 16;
  __shared__ float As[16][65];
  __shared__ float Bs[16][65];
  int tid = threadIdx.x;
  int bm = blockIdx.y * 64, bn = blockIdx.x * 64;
  int tcol = tid & 15, trow = tid >> 4;
  float acc[4][4] = {};
  for (int k0 = 0; k0 < K; k0 += BK) {
#pragma unroll
    for (int i = 0; i < 4; i++) {
      int r = (tid >> 4) + i * 16, c = tid & 15;
      As[c][r] = A[(size_t)(bm + r) * K + k0 + c];
    }
#pragma unroll
    for (int i = 0; i < 4; i++) {
      int r = (tid >> 6) + i * 4, c = tid & 63;
      Bs[r][c] = Bm[(size_t)(k0 + r) * N + bn + c];
    }
    __syncthreads();
#pragma unroll
    for (int kk = 0; kk < BK; kk++) {
      float a[4], b[4];
#pragma unroll
      for (int i = 0; i < 4; i++) a[i] = As[kk][trow * 4 + i];
#pragma unroll
      for (int j = 0; j < 4; j++) b[j] = Bs[kk][tcol * 4 + j];
#pragma unroll
      for (int i = 0; i < 4; i++)
#pragma unroll
        for (int j = 0; j < 4; j++) acc[i][j] = fmaf(a[i], b[j], acc[i][j]);
    }
    __syncthreads();
  }
#pragma unroll
  for (int i = 0; i < 4; i++)
#pragma unroll
    for (int j = 0; j < 4; j++)
      C[(size_t)(bm + trow * 4 + i) * N + bn + tcol * 4 + j] = acc[i][j];
}

// ---------------- rmsnorm over rows of length 512, in place ------------------
__global__ __launch_bounds__(256) void rmsnorm512(float* __restrict__ x,
                                                  const float* __restrict__ g) {
  int row = blockIdx.x;
  float* p = x + (size_t)row * 512;
  int t = threadIdx.x;
  float v0 = p[t], v1 = p[t + 256];
  __shared__ float red[256];
  red[t] = v0 * v0 + v1 * v1;
  __syncthreads();
  for (int s = 128; s > 0; s >>= 1) {
    if (t < s) red[t] += red[t + s];
    __syncthreads();
  }
  float r = rsqrtf(red[0] / 512.f + 1e-6f);
  p[t] = v0 * r * g[t];
  p[t + 256] = v1 * r * g[t + 256];
}

// ---------------- rope on rows x 64 (position = row % S_), in place ----------
__global__ void rope64(float* __restrict__ x, int rows) {
  int i = blockIdx.x * blockDim.x + threadIdx.x;
  if (i >= rows * 32) return;
  int r = i >> 5, j = i & 31;
  int s = r & (S_ - 1);
  float freq = powf(10000.f, -(float)(2 * j) / 64.f);
  float ang = (float)s * freq;
  float c = cosf(ang), sn = sinf(ang);
  size_t base = (size_t)r * 64 + 2 * j;
  float x0 = x[base], x1 = x[base + 1];
  x[base] = x0 * c - x1 * sn;
  x[base + 1] = x1 * c + x0 * sn;
}

// ------------- rope on q rope-section: q is 4096 x 3072, cols h*192+128.. ----
__global__ void rope_q(float* __restrict__ q) {
  int i = blockIdx.x * blockDim.x + threadIdx.x;
  int j = i & 31;
  int h = (i >> 5) & 15;
  int r = i >> 9;
  if (r >= 4096) return;
  int s = r & (S_ - 1);
  float freq = powf(10000.f, -(float)(2 * j) / 64.f);
  float ang = (float)s * freq;
  float c = cosf(ang), sn = sinf(ang);
  size_t base = (size_t)r * 3072 + h * 192 + 128 + 2 * j;
  float x0 = q[base], x1 = q[base + 1];
  q[base] = x0 * c - x1 * sn;
  q[base + 1] = x1 * c + x0 * sn;
}

// ------------- pack Q (scaled) and K (nope||rope) to bf16 [BH][S][192] -------
// scale*log2e = (1/sqrt(192)) * 1.4426950408889634
#define QSCALE 0.1041177003f
__global__ void pack_qk(const float* __restrict__ q, const float* __restrict__ kn,
                        const float* __restrict__ kr, bf16_t* __restrict__ Qp,
                        bf16_t* __restrict__ Kp) {
  int idx = blockIdx.x * 256 + threadIdx.x;
  if (idx >= 32 * S_ * 192) return;
  int f = idx % 192;
  int s = (idx / 192) & (S_ - 1);
  int bh = idx / (192 * S_);
  int b = bh >> 4, h = bh & 15;
  size_t rowq = (size_t)(b * S_ + s);
  Qp[idx] = (bf16_t)(q[rowq * 3072 + h * 192 + f] * QSCALE);
  float kv = (f < 128) ? kn[rowq * 2048 + h * 128 + f] : kr[rowq * 64 + (f - 128)];
  Kp[idx] = (bf16_t)kv;
}

// ------------- pack V transposed to bf16: Vt[BH][128][S] ---------------------
__global__ __launch_bounds__(256) void pack_vt(const float* __restrict__ v,
                                               bf16_t* __restrict__ Vt) {
  __shared__ float t[32][33];
  int bh = blockIdx.z;
  int b = bh >> 4, h = bh & 15;
  int s0 = blockIdx.x * 32, d0 = blockIdx.y * 32;
  int tx = threadIdx.x, ty = threadIdx.y;
#pragma unroll
  for (int i = 0; i < 4; i++) {
    int s = s0 + ty + i * 8;
    t[ty + i * 8][tx] = v[((size_t)(b * S_ + s)) * 2048 + h * 128 + d0 + tx];
  }
  __syncthreads();
#pragma unroll
  for (int i = 0; i < 4; i++) {
    int d = d0 + ty + i * 8;
    Vt[((size_t)bh * 128 + d) * S_ + s0 + tx] = (bf16_t)t[tx][ty + i * 8];
  }
}

// ---------------- flash attention: bf16 MFMA, online softmax -----------------
// grid (32 qtiles, 16 h, 2 b), 256 threads = 4 waves, each wave owns 16 q rows.
__global__ __launch_bounds__(256) void flash_attn(
    const bf16_t* __restrict__ Qp,  // [BH][S][192], pre-scaled by QSCALE
    const bf16_t* __restrict__ Kp,  // [BH][S][192]
    const bf16_t* __restrict__ Vt,  // [BH][128][S]
    float* __restrict__ o) {        // [B*S][2048]
  int qt = blockIdx.x;
  int h = blockIdx.y;
  int b = blockIdx.z;
  int bh = b * H_ + h;
  int w = threadIdx.x >> 6;
  int lane = threadIdx.x & 63;
  int lrow = lane & 15;   // A-row / B-col index within 16
  int lgrp = lane >> 4;   // k-group

  const int qb = qt * 64 + w * 16;  // this wave's q base row
  const bf16_t* Qb = Qp + ((size_t)bh * S_ + qb) * 192;
  const bf16_t* Kb = Kp + (size_t)bh * S_ * 192;
  const bf16_t* Vb = Vt + (size_t)bh * 128 * S_;

  // Q fragments: lane holds Q[qb+lrow][ks*32 + lgrp*8 .. +7]
  bf16x8 qf[6];
#pragma unroll
  for (int ks = 0; ks < 6; ks++)
    qf[ks] = *(const bf16x8*)(Qb + (size_t)lrow * 192 + ks * 32 + lgrp * 8);

  f32x4 acc[8];
#pragma unroll
  for (int i = 0; i < 8; i++) acc[i] = f32x4{0.f, 0.f, 0.f, 0.f};
  float mrow[4], lsum[4];
#pragma unroll
  for (int r = 0; r < 4; r++) { mrow[r] = -1e30f; lsum[r] = 0.f; }

  __shared__ alignas(16) bf16_t psh[4][16 * 64];  // per-wave P staging
  bf16_t* pw = &psh[w][0];

  const int nkt = qt + 1;  // causal: tiles 0..qt
  for (int kt = 0; kt < nkt; kt++) {
    // ---- score tile S (16 rows x 64 keys) ----
    const bf16_t* Kt = Kb + (size_t)kt * 64 * 192;
    f32x4 sc[4];
#pragma unroll
    for (int cb = 0; cb < 4; cb++) {
      f32x4 s = f32x4{0.f, 0.f, 0.f, 0.f};
      const bf16_t* kp = Kt + (size_t)(cb * 16 + lrow) * 192 + lgrp * 8;
#pragma unroll
      for (int ks = 0; ks < 6; ks++) {
        bf16x8 kf = *(const bf16x8*)(kp + ks * 32);
        s = __builtin_amdgcn_mfma_f32_16x16x32_bf16(qf[ks], kf, s, 0, 0, 0);
      }
      sc[cb] = s;
    }
    // causal mask (only last tile can cross the diagonal)
    if (kt == nkt - 1) {
#pragma unroll
      for (int cb = 0; cb < 4; cb++)
#pragma unroll
        for (int r = 0; r < 4; r++) {
          int col = kt * 64 + cb * 16 + lrow;
          int row = qb + lgrp * 4 + r;
          if (col > row) sc[cb][r] = -1e30f;
        }
    }
    // ---- online softmax (scores already in log2 domain) ----
#pragma unroll
    for (int r = 0; r < 4; r++) {
      float v = fmaxf(fmaxf(sc[0][r], sc[1][r]), fmaxf(sc[2][r], sc[3][r]));
      v = fmaxf(v, __shfl_xor(v, 1));
      v = fmaxf(v, __shfl_xor(v, 2));
      v = fmaxf(v, __shfl_xor(v, 4));
      v = fmaxf(v, __shfl_xor(v, 8));
      float mn = fmaxf(mrow[r], v);
      float alpha = exp2f(mrow[r] - mn);
      mrow[r] = mn;
      lsum[r] *= alpha;
#pragma unroll
      for (int cb = 0; cb < 8; cb++) acc[cb][r] *= alpha;
      float ps = 0.f;
#pragma unroll
      for (int cb = 0; cb < 4; cb++) {
        float e = exp2f(sc[cb][r] - mn);
        sc[cb][r] = e;
        ps += e;
      }
      ps += __shfl_xor(ps, 1);
      ps += __shfl_xor(ps, 2);
      ps += __shfl_xor(ps, 4);
      ps += __shfl_xor(ps, 8);
      lsum[r] += ps;
    }
    // ---- stage P to LDS (bf16, XOR-swizzled rows) ----
    __syncthreads();
#pragma unroll
    for (int r = 0; r < 4; r++) {
      int row = lgrp * 4 + r;
#pragma unroll
      for (int cb = 0; cb < 4; cb++) {
        int byte = (row * 128 + (cb * 16 + lrow) * 2) ^ ((row & 7) << 4);
        *(bf16_t*)((char*)pw + byte) = (bf16_t)sc[cb][r];
      }
    }
    __syncthreads();
    // P fragments: lane holds P[lrow][ks*32 + lgrp*8 .. +7]
    bf16x8 pa[2];
#pragma unroll
    for (int ks = 0; ks < 2; ks++) {
      int byte = (lrow * 128 + ks * 64 + lgrp * 16) ^ ((lrow & 7) << 4);
      pa[ks] = *(const bf16x8*)((char*)pw + byte);
    }
    // ---- O += P @ V ----
    const bf16_t* Vtile = Vb + (size_t)kt * 64;
#pragma unroll
    for (int cbv = 0; cbv < 8; cbv++) {
      const bf16_t* vp = Vtile + (size_t)(cbv * 16 + lrow) * S_ + lgrp * 8;
      f32x4 a = acc[cbv];
#pragma unroll
      for (int ks = 0; ks < 2; ks++) {
        bf16x8 vf = *(const bf16x8*)(vp + ks * 32);
        a = __builtin_amdgcn_mfma_f32_16x16x32_bf16(pa[ks], vf, a, 0, 0, 0);
      }
      acc[cbv] = a;
    }
  }
  // ---- normalize + store ----
#pragma unroll
  for (int r = 0; r < 4; r++) {
    float inv = 1.f / lsum[r];
    int row = qb + lgrp * 4 + r;
    float* op = o + (size_t)(b * S_ + row) * 2048 + h * 128;
#pragma unroll
    for (int cbv = 0; cbv < 8; cbv++)
      op[cbv * 16 + lrow] = acc[cbv][r] * inv;
  }
}

extern "C" void kernel_launch(void* const* d_in, const int* in_sizes, int n_in,
                              void* d_out, int out_size, void* d_ws, size_t ws_size,
                              hipStream_t stream) {
  const float* x        = (const float*)d_in[0];
  const float* w_dq     = (const float*)d_in[1];
  const float* g_q      = (const float*)d_in[2];
  const float* w_uq     = (const float*)d_in[3];
  const float* w_dkv    = (const float*)d_in[4];
  const float* g_kv     = (const float*)d_in[5];
  const float* w_ukrope = (const float*)d_in[6];
  const float* w_uv     = (const float*)d_in[7];
  const float* w_uknope = (const float*)d_in[8];
  const float* w_o      = (const float*)d_in[9];
  float* out = (float*)d_out;

  const int M = 4096;
  float* ws = (float*)d_ws;
  // fp32 intermediates
  float* q    = ws;                        // 4096*3072
  float* kn   = q + (size_t)M * 3072;      // 4096*2048
  float* v    = kn + (size_t)M * 2048;     // 4096*2048
  float* kr   = v + (size_t)M * 2048;      // 4096*64
  float* ao   = kr + (size_t)M * 64;       // 4096*2048
  float* y_q  = ao + (size_t)M * 2048;     // 4096*512 (dead after up-proj)
  float* y_kv = y_q + (size_t)M * 512;     // 4096*512 (dead after up-proj)
  // bf16 packs overlap the dead y_q/y_kv region
  bf16_t* Qp = (bf16_t*)y_q;                    // 32*2048*192 bf16
  bf16_t* Kp = Qp + (size_t)32 * S_ * 192;      // 32*2048*192 bf16
  bf16_t* Vt = Kp + (size_t)32 * S_ * 192;      // 32*128*2048 bf16

  dim3 blk(256);
  gemm_f32<<<dim3(512 / 64, M / 64), blk, 0, stream>>>(x, w_dq, y_q, M, 512, 2048);
  gemm_f32<<<dim3(512 / 64, M / 64), blk, 0, stream>>>(x, w_dkv, y_kv, M, 512, 2048);
  gemm_f32<<<dim3(64 / 64, M / 64), blk, 0, stream>>>(x, w_ukrope, kr, M, 64, 2048);
  rmsnorm512<<<M, blk, 0, stream>>>(y_q, g_q);
  rmsnorm512<<<M, blk, 0, stream>>>(y_kv, g_kv);
  gemm_f32<<<dim3(3072 / 64, M / 64), blk, 0, stream>>>(y_q, w_uq, q, M, 3072, 512);
  gemm_f32<<<dim3(2048 / 64, M / 64), blk, 0, stream>>>(y_kv, w_uknope, kn, M, 2048, 512);
  gemm_f32<<<dim3(2048 / 64, M / 64), blk, 0, stream>>>(y_kv, w_uv, v, M, 2048, 512);
  rope64<<<(M * 32 + 255) / 256, blk, 0, stream>>>(kr, M);
  rope_q<<<(M * 16 * 32 + 255) / 256, blk, 0, stream>>>(q);
  // pack to bf16 (y_q/y_kv are dead now)
  pack_qk<<<(32 * S_ * 192 + 255) / 256, blk, 0, stream>>>(q, kn, kr, Qp, Kp);
  pack_vt<<<dim3(S_ / 32, 4, 32), dim3(32, 8), 0, stream>>>(v, Vt);
  // flash attention
  flash_attn<<<dim3(32, 16, 2), blk, 0, stream>>>(Qp, Kp, Vt, ao);
  // output projection
  gemm_f32<<<dim3(2048 / 64, M / 64), blk, 0, stream>>>(ao, w_o, out, M, 2048, 2048);
}

// Round 5
// 1101.742 us; speedup vs baseline: 8.2921x; 2.3303x over previous
//
#include <hip/hip_runtime.h>
#include <hip/hip_bf16.h>

// MLA: bf16 MFMA GEMMs (m97-structure) + bf16 MFMA flash attention.
// B=2, S=2048, E=2048, C=512, H=16, Dn=128, Dr=64.

#define S_ 2048
#define H_ 16

typedef __bf16 bf16_t;
typedef __bf16 bf16x8 __attribute__((ext_vector_type(8)));
typedef __bf16 bf16x4_t __attribute__((ext_vector_type(4)));
typedef float f32x4 __attribute__((ext_vector_type(4)));

#define ASYNC_COPY16(gsrc, ldst)                                              \
  __builtin_amdgcn_global_load_lds(                                           \
      (const __attribute__((address_space(1))) void*)(gsrc),                  \
      (__attribute__((address_space(3))) void*)(ldst), 16, 0, 0)

// scale*log2e = (1/sqrt(192)) * 1.4426950408889634
#define QSCALE 0.1041177003f

// ---------------- fp32 -> bf16 convert (vectorized) --------------------------
__global__ void conv_bf16(const float* __restrict__ in, bf16_t* __restrict__ out,
                          int n4) {
  int i = blockIdx.x * 256 + threadIdx.x;
  if (i >= n4) return;
  float4 v = ((const float4*)in)[i];
  bf16x4_t o = {(bf16_t)v.x, (bf16_t)v.y, (bf16_t)v.z, (bf16_t)v.w};
  ((bf16x4_t*)out)[i] = o;
}

// ---------------- transpose+convert weights: [K][N] f32 -> [N][K] bf16 -------
__global__ __launch_bounds__(256) void transw(const float* __restrict__ in,
                                              bf16_t* __restrict__ out, int K,
                                              int N) {
  __shared__ float t[32][33];
  int k0 = blockIdx.y * 32, n0 = blockIdx.x * 32;
  int tx = threadIdx.x, ty = threadIdx.y;
#pragma unroll
  for (int i = 0; i < 4; i++)
    t[ty + i * 8][tx] = in[(size_t)(k0 + ty + i * 8) * N + n0 + tx];
  __syncthreads();
#pragma unroll
  for (int i = 0; i < 4; i++)
    out[(size_t)(n0 + ty + i * 8) * K + k0 + tx] = (bf16_t)t[tx][ty + i * 8];
}

// ---------------- bf16 MFMA GEMM: C = A(MxK) @ Bt(NxK)^T ---------------------
// 128x128 tile, BK=32, 4 waves (2x2), global_load_lds staging with XOR chunk
// swizzle (LDS(row,c) holds A[row][c ^ ((row>>1)&3)] at 16B-chunk granularity).
// MODE 0: C[row*N+col] = val (OT float or bf16)
// MODE 1: Kp layout: out[((b*16+h)*2048+s)*192 + d], h=col>>7, d=col&127
// MODE 2: Qp layout: out[((b*16+h)*2048+s)*192 + f]*QSCALE, h=col/192, f=col%192
template <typename OT, int MODE>
__global__ __launch_bounds__(256) void gemm_bt(const bf16_t* __restrict__ A,
                                               const bf16_t* __restrict__ Bt,
                                               OT* __restrict__ C, int M, int N,
                                               int K) {
  __shared__ bf16_t Asm[128 * 32];
  __shared__ bf16_t Bsm[128 * 32];
  int tid = threadIdx.x;
  int w = tid >> 6, lane = tid & 63;
  int lrow = lane & 15, lgrp = lane >> 4;
  int wr = w >> 1, wc = w & 1;
  int bm = blockIdx.y * 128, bn = blockIdx.x * 128;

  const bf16_t* Ab = A + (size_t)bm * K;
  const bf16_t* Bb = Bt + (size_t)bn * K;

  // staging geometry: lane covers (row = w*32 + j*16 + (lane>>2), chunk lane&3)
  int srow = (w << 5) + (lane >> 2);
  int schunk = lane & 3;

  // ds_read byte offsets (loop-invariant)
  int ra[4], rb[4];
#pragma unroll
  for (int m = 0; m < 4; m++) {
    int rowA = wr * 64 + m * 16 + lrow;
    ra[m] = rowA * 64 + ((lgrp * 16) ^ (((rowA >> 1) & 3) << 4));
    int rowB = wc * 64 + m * 16 + lrow;
    rb[m] = rowB * 64 + ((lgrp * 16) ^ (((rowB >> 1) & 3) << 4));
  }

  f32x4 acc[4][4] = {};

  for (int k0 = 0; k0 < K; k0 += 32) {
#pragma unroll
    for (int j = 0; j < 2; j++) {
      int row = srow + j * 16;
      int cs = schunk ^ ((row >> 1) & 3);
      ASYNC_COPY16(Ab + (size_t)row * K + k0 + cs * 8,
                   (char*)Asm + (w << 11) + (j << 10));
      ASYNC_COPY16(Bb + (size_t)row * K + k0 + cs * 8,
                   (char*)Bsm + (w << 11) + (j << 10));
    }
    __syncthreads();
    bf16x8 af[4], bfr[4];
#pragma unroll
    for (int m = 0; m < 4; m++) {
      af[m] = *(const bf16x8*)((const char*)Asm + ra[m]);
      bfr[m] = *(const bf16x8*)((const char*)Bsm + rb[m]);
    }
#pragma unroll
    for (int m = 0; m < 4; m++)
#pragma unroll
      for (int n = 0; n < 4; n++)
        acc[m][n] =
            __builtin_amdgcn_mfma_f32_16x16x32_bf16(af[m], bfr[n], acc[m][n], 0, 0, 0);
    __syncthreads();
  }

#pragma unroll
  for (int m = 0; m < 4; m++)
#pragma unroll
    for (int n = 0; n < 4; n++)
#pragma unroll
      for (int j = 0; j < 4; j++) {
        int row = bm + wr * 64 + m * 16 + lgrp * 4 + j;
        int col = bn + wc * 64 + n * 16 + lrow;
        float val = acc[m][n][j];
        if (MODE == 0) {
          C[(size_t)row * N + col] = (OT)val;
        } else if (MODE == 1) {
          int b = row >> 11, s = row & (S_ - 1);
          int h = col >> 7, d = col & 127;
          ((bf16_t*)C)[((size_t)((b << 4) + h) * S_ + s) * 192 + d] = (bf16_t)val;
        } else {
          int b = row >> 11, s = row & (S_ - 1);
          unsigned h = (unsigned)col / 192u, f = (unsigned)col % 192u;
          ((bf16_t*)C)[((size_t)((b << 4) + h) * S_ + s) * 192 + f] =
              (bf16_t)(val * QSCALE);
        }
      }
}

// ---------------- fp32 GEMM (kept for the tiny w_ukrope projection) ----------
__global__ __launch_bounds__(256) void gemm_f32(
    const float* __restrict__ A, const float* __restrict__ Bm,
    float* __restrict__ C, int M, int N, int K) {
  const int BK = 16;
  __shared__ float As[16][65];
  __shared__ float Bs[16][65];
  int tid = threadIdx.x;
  int bm = blockIdx.y * 64, bn = blockIdx.x * 64;
  int tcol = tid & 15, trow = tid >> 4;
  float acc[4][4] = {};
  for (int k0 = 0; k0 < K; k0 += BK) {
#pragma unroll
    for (int i = 0; i < 4; i++) {
      int r = (tid >> 4) + i * 16, c = tid & 15;
      As[c][r] = A[(size_t)(bm + r) * K + k0 + c];
    }
#pragma unroll
    for (int i = 0; i < 4; i++) {
      int r = (tid >> 6) + i * 4, c = tid & 63;
      Bs[r][c] = Bm[(size_t)(k0 + r) * N + bn + c];
    }
    __syncthreads();
#pragma unroll
    for (int kk = 0; kk < BK; kk++) {
      float a[4], b[4];
#pragma unroll
      for (int i = 0; i < 4; i++) a[i] = As[kk][trow * 4 + i];
#pragma unroll
      for (int j = 0; j < 4; j++) b[j] = Bs[kk][tcol * 4 + j];
#pragma unroll
      for (int i = 0; i < 4; i++)
#pragma unroll
        for (int j = 0; j < 4; j++) acc[i][j] = fmaf(a[i], b[j], acc[i][j]);
    }
    __syncthreads();
  }
#pragma unroll
  for (int i = 0; i < 4; i++)
#pragma unroll
    for (int j = 0; j < 4; j++)
      C[(size_t)(bm + trow * 4 + i) * N + bn + tcol * 4 + j] = acc[i][j];
}

// ---------------- rmsnorm over bf16 rows of length 512, in place -------------
__global__ __launch_bounds__(256) void rmsnorm512_b(bf16_t* __restrict__ x,
                                                    const float* __restrict__ g) {
  int row = blockIdx.x;
  bf16_t* p = x + (size_t)row * 512;
  int t = threadIdx.x;
  float v0 = (float)p[t], v1 = (float)p[t + 256];
  __shared__ float red[256];
  red[t] = v0 * v0 + v1 * v1;
  __syncthreads();
  for (int s = 128; s > 0; s >>= 1) {
    if (t < s) red[t] += red[t + s];
    __syncthreads();
  }
  float r = rsqrtf(red[0] / 512.f + 1e-6f);
  p[t] = (bf16_t)(v0 * r * g[t]);
  p[t + 256] = (bf16_t)(v1 * r * g[t + 256]);
}

// ---------------- rope on kr fp32 rows x 64, in place ------------------------
__global__ void rope64(float* __restrict__ x, int rows) {
  int i = blockIdx.x * blockDim.x + threadIdx.x;
  if (i >= rows * 32) return;
  int r = i >> 5, j = i & 31;
  int s = r & (S_ - 1);
  float freq = powf(10000.f, -(float)(2 * j) / 64.f);
  float ang = (float)s * freq;
  float c = cosf(ang), sn = sinf(ang);
  size_t base = (size_t)r * 64 + 2 * j;
  float x0 = x[base], x1 = x[base + 1];
  x[base] = x0 * c - x1 * sn;
  x[base + 1] = x1 * c + x0 * sn;
}

// ---------------- rope on Qp rope-section in place (bf16) --------------------
__global__ void rope_qp(bf16_t* __restrict__ Qp) {
  int i = blockIdx.x * 256 + threadIdx.x;  // 32*2048*32 pairs
  if (i >= 32 * S_ * 32) return;
  int j = i & 31;
  int s = (i >> 5) & (S_ - 1);
  int bh = i >> 16;
  float freq = powf(10000.f, -(float)(2 * j) / 64.f);
  float ang = (float)s * freq;
  float c = cosf(ang), sn = sinf(ang);
  size_t base = ((size_t)bh * S_ + s) * 192 + 128 + 2 * j;
  float x0 = (float)Qp[base], x1 = (float)Qp[base + 1];
  Qp[base] = (bf16_t)(x0 * c - x1 * sn);
  Qp[base + 1] = (bf16_t)(x1 * c + x0 * sn);
}

// ---------------- broadcast rope'd kr into Kp rope section ------------------
__global__ void pack_kr(const float* __restrict__ kr, bf16_t* __restrict__ Kp) {
  int i = blockIdx.x * 256 + threadIdx.x;  // 32*2048*64
  if (i >= 32 * S_ * 64) return;
  int f = i & 63;
  int s = (i >> 6) & (S_ - 1);
  int bh = i >> 17;
  int b = bh >> 4;
  Kp[((size_t)bh * S_ + s) * 192 + 128 + f] =
      (bf16_t)kr[((size_t)(b * S_ + s)) * 64 + f];
}

// ---------------- pack V (bf16) transposed: Vt[BH][128][S] -------------------
__global__ __launch_bounds__(256) void pack_vt(const bf16_t* __restrict__ v,
                                               bf16_t* __restrict__ Vt) {
  __shared__ float t[32][33];
  int bh = blockIdx.z;
  int b = bh >> 4, h = bh & 15;
  int s0 = blockIdx.x * 32, d0 = blockIdx.y * 32;
  int tx = threadIdx.x, ty = threadIdx.y;
#pragma unroll
  for (int i = 0; i < 4; i++) {
    int s = s0 + ty + i * 8;
    t[ty + i * 8][tx] = (float)v[((size_t)(b * S_ + s)) * 2048 + h * 128 + d0 + tx];
  }
  __syncthreads();
#pragma unroll
  for (int i = 0; i < 4; i++) {
    int d = d0 + ty + i * 8;
    Vt[((size_t)bh * 128 + d) * S_ + s0 + tx] = (bf16_t)t[tx][ty + i * 8];
  }
}

// ---------------- flash attention: bf16 MFMA, online softmax -----------------
__global__ __launch_bounds__(256) void flash_attn(
    const bf16_t* __restrict__ Qp,  // [BH][S][192], pre-scaled by QSCALE
    const bf16_t* __restrict__ Kp,  // [BH][S][192]
    const bf16_t* __restrict__ Vt,  // [BH][128][S]
    bf16_t* __restrict__ o) {       // [B*S][2048] bf16
  int qt = blockIdx.x;
  int h = blockIdx.y;
  int b = blockIdx.z;
  int bh = b * H_ + h;
  int w = threadIdx.x >> 6;
  int lane = threadIdx.x & 63;
  int lrow = lane & 15;
  int lgrp = lane >> 4;

  const int qb = qt * 64 + w * 16;
  const bf16_t* Qb = Qp + ((size_t)bh * S_ + qb) * 192;
  const bf16_t* Kb = Kp + (size_t)bh * S_ * 192;
  const bf16_t* Vb = Vt + (size_t)bh * 128 * S_;

  bf16x8 qf[6];
#pragma unroll
  for (int ks = 0; ks < 6; ks++)
    qf[ks] = *(const bf16x8*)(Qb + (size_t)lrow * 192 + ks * 32 + lgrp * 8);

  f32x4 acc[8];
#pragma unroll
  for (int i = 0; i < 8; i++) acc[i] = f32x4{0.f, 0.f, 0.f, 0.f};
  float mrow[4], lsum[4];
#pragma unroll
  for (int r = 0; r < 4; r++) { mrow[r] = -1e30f; lsum[r] = 0.f; }

  __shared__ alignas(16) bf16_t psh[4][16 * 64];
  bf16_t* pw = &psh[w][0];

  const int nkt = qt + 1;
  for (int kt = 0; kt < nkt; kt++) {
    const bf16_t* Kt = Kb + (size_t)kt * 64 * 192;
    f32x4 sc[4];
#pragma unroll
    for (int cb = 0; cb < 4; cb++) {
      f32x4 s = f32x4{0.f, 0.f, 0.f, 0.f};
      const bf16_t* kp = Kt + (size_t)(cb * 16 + lrow) * 192 + lgrp * 8;
#pragma unroll
      for (int ks = 0; ks < 6; ks++) {
        bf16x8 kf = *(const bf16x8*)(kp + ks * 32);
        s = __builtin_amdgcn_mfma_f32_16x16x32_bf16(qf[ks], kf, s, 0, 0, 0);
      }
      sc[cb] = s;
    }
    if (kt == nkt - 1) {
#pragma unroll
      for (int cb = 0; cb < 4; cb++)
#pragma unroll
        for (int r = 0; r < 4; r++) {
          int col = kt * 64 + cb * 16 + lrow;
          int row = qb + lgrp * 4 + r;
          if (col > row) sc[cb][r] = -1e30f;
        }
    }
#pragma unroll
    for (int r = 0; r < 4; r++) {
      float v = fmaxf(fmaxf(sc[0][r], sc[1][r]), fmaxf(sc[2][r], sc[3][r]));
      v = fmaxf(v, __shfl_xor(v, 1));
      v = fmaxf(v, __shfl_xor(v, 2));
      v = fmaxf(v, __shfl_xor(v, 4));
      v = fmaxf(v, __shfl_xor(v, 8));
      float mn = fmaxf(mrow[r], v);
      float alpha = exp2f(mrow[r] - mn);
      mrow[r] = mn;
      lsum[r] *= alpha;
#pragma unroll
      for (int cb = 0; cb < 8; cb++) acc[cb][r] *= alpha;
      float ps = 0.f;
#pragma unroll
      for (int cb = 0; cb < 4; cb++) {
        float e = exp2f(sc[cb][r] - mn);
        sc[cb][r] = e;
        ps += e;
      }
      ps += __shfl_xor(ps, 1);
      ps += __shfl_xor(ps, 2);
      ps += __shfl_xor(ps, 4);
      ps += __shfl_xor(ps, 8);
      lsum[r] += ps;
    }
    __syncthreads();
#pragma unroll
    for (int r = 0; r < 4; r++) {
      int row = lgrp * 4 + r;
#pragma unroll
      for (int cb = 0; cb < 4; cb++) {
        int byte = (row * 128 + (cb * 16 + lrow) * 2) ^ ((row & 7) << 4);
        *(bf16_t*)((char*)pw + byte) = (bf16_t)sc[cb][r];
      }
    }
    __syncthreads();
    bf16x8 pa[2];
#pragma unroll
    for (int ks = 0; ks < 2; ks++) {
      int byte = (lrow * 128 + ks * 64 + lgrp * 16) ^ ((lrow & 7) << 4);
      pa[ks] = *(const bf16x8*)((char*)pw + byte);
    }
    const bf16_t* Vtile = Vb + (size_t)kt * 64;
#pragma unroll
    for (int cbv = 0; cbv < 8; cbv++) {
      const bf16_t* vp = Vtile + (size_t)(cbv * 16 + lrow) * S_ + lgrp * 8;
      f32x4 a = acc[cbv];
#pragma unroll
      for (int ks = 0; ks < 2; ks++) {
        bf16x8 vf = *(const bf16x8*)(vp + ks * 32);
        a = __builtin_amdgcn_mfma_f32_16x16x32_bf16(pa[ks], vf, a, 0, 0, 0);
      }
      acc[cbv] = a;
    }
  }
#pragma unroll
  for (int r = 0; r < 4; r++) {
    float inv = 1.f / lsum[r];
    int row = qb + lgrp * 4 + r;
    bf16_t* op = o + (size_t)(b * S_ + row) * 2048 + h * 128;
#pragma unroll
    for (int cbv = 0; cbv < 8; cbv++)
      op[cbv * 16 + lrow] = (bf16_t)(acc[cbv][r] * inv);
  }
}

extern "C" void kernel_launch(void* const* d_in, const int* in_sizes, int n_in,
                              void* d_out, int out_size, void* d_ws, size_t ws_size,
                              hipStream_t stream) {
  const float* x        = (const float*)d_in[0];
  const float* w_dq     = (const float*)d_in[1];
  const float* g_q      = (const float*)d_in[2];
  const float* w_uq     = (const float*)d_in[3];
  const float* w_dkv    = (const float*)d_in[4];
  const float* g_kv     = (const float*)d_in[5];
  const float* w_ukrope = (const float*)d_in[6];
  const float* w_uv     = (const float*)d_in[7];
  const float* w_uknope = (const float*)d_in[8];
  const float* w_o      = (const float*)d_in[9];
  float* out = (float*)d_out;

  const int M = 4096;
  float* kr = (float*)d_ws;                      // 4096*64 f32
  bf16_t* wb = (bf16_t*)(kr + (size_t)M * 64);   // bf16 arena
  size_t off = 0;
  bf16_t* xb   = wb + off; off += (size_t)M * 2048;   // also reused as ao
  bf16_t* vb   = wb + off; off += (size_t)M * 2048;
  bf16_t* y_q  = wb + off; off += (size_t)M * 512;
  bf16_t* y_kv = wb + off; off += (size_t)M * 512;
  bf16_t* dq_t = wb + off; off += (size_t)512 * 2048;
  bf16_t* dkv_t= wb + off; off += (size_t)512 * 2048;
  bf16_t* uq_t = wb + off; off += (size_t)3072 * 512;
  bf16_t* ukn_t= wb + off; off += (size_t)2048 * 512;
  bf16_t* uv_t = wb + off; off += (size_t)2048 * 512;
  bf16_t* o_t  = wb + off; off += (size_t)2048 * 2048;
  bf16_t* Qp   = wb + off; off += (size_t)32 * S_ * 192;
  bf16_t* Kp   = wb + off; off += (size_t)32 * S_ * 192;
  bf16_t* Vt   = wb + off; off += (size_t)32 * 128 * S_;
  bf16_t* ao = xb;  // xb dead after down-projections

  dim3 blk(256);
  dim3 tb(32, 8);
  // pack x and weights to bf16
  conv_bf16<<<(M * 2048 / 4 + 255) / 256, blk, 0, stream>>>(x, xb, M * 2048 / 4);
  transw<<<dim3(512 / 32, 2048 / 32), tb, 0, stream>>>(w_dq, dq_t, 2048, 512);
  transw<<<dim3(512 / 32, 2048 / 32), tb, 0, stream>>>(w_dkv, dkv_t, 2048, 512);
  transw<<<dim3(3072 / 32, 512 / 32), tb, 0, stream>>>(w_uq, uq_t, 512, 3072);
  transw<<<dim3(2048 / 32, 512 / 32), tb, 0, stream>>>(w_uknope, ukn_t, 512, 2048);
  transw<<<dim3(2048 / 32, 512 / 32), tb, 0, stream>>>(w_uv, uv_t, 512, 2048);
  transw<<<dim3(2048 / 32, 2048 / 32), tb, 0, stream>>>(w_o, o_t, 2048, 2048);
  // rope base (tiny, fp32 path)
  gemm_f32<<<dim3(1, M / 64), blk, 0, stream>>>(x, w_ukrope, kr, M, 64, 2048);
  // down-projections
  gemm_bt<bf16_t, 0><<<dim3(4, 32), blk, 0, stream>>>(xb, dq_t, y_q, M, 512, 2048);
  gemm_bt<bf16_t, 0><<<dim3(4, 32), blk, 0, stream>>>(xb, dkv_t, y_kv, M, 512, 2048);
  rmsnorm512_b<<<M, blk, 0, stream>>>(y_q, g_q);
  rmsnorm512_b<<<M, blk, 0, stream>>>(y_kv, g_kv);
  // up-projections (fused into attention layouts where possible)
  gemm_bt<bf16_t, 2><<<dim3(24, 32), blk, 0, stream>>>(y_q, uq_t, Qp, M, 3072, 512);
  gemm_bt<bf16_t, 1><<<dim3(16, 32), blk, 0, stream>>>(y_kv, ukn_t, Kp, M, 2048, 512);
  gemm_bt<bf16_t, 0><<<dim3(16, 32), blk, 0, stream>>>(y_kv, uv_t, vb, M, 2048, 512);
  // rope + remaining packs
  rope64<<<(M * 32 + 255) / 256, blk, 0, stream>>>(kr, M);
  rope_qp<<<(32 * S_ * 32 + 255) / 256, blk, 0, stream>>>(Qp);
  pack_kr<<<(32 * S_ * 64 + 255) / 256, blk, 0, stream>>>(kr, Kp);
  pack_vt<<<dim3(S_ / 32, 4, 32), tb, 0, stream>>>(vb, Vt);
  // flash attention
  flash_attn<<<dim3(32, 16, 2), blk, 0, stream>>>(Qp, Kp, Vt, ao);
  // output projection
  gemm_bt<float, 0><<<dim3(16, 32), blk, 0, stream>>>(ao, o_t, out, M, 2048, 2048);
}

// Round 6
// 617.941 us; speedup vs baseline: 14.7842x; 1.7829x over previous
//
#include <hip/hip_runtime.h>
#include <hip/hip_bf16.h>

// MLA: bf16 MFMA GEMMs + LDS-staged, pair-balanced bf16 MFMA flash attention.
// B=2, S=2048, E=2048, C=512, H=16, Dn=128, Dr=64.

#define S_ 2048
#define H_ 16

typedef __bf16 bf16_t;
typedef __bf16 bf16x8 __attribute__((ext_vector_type(8)));
typedef __bf16 bf16x4_t __attribute__((ext_vector_type(4)));
typedef float f32x4 __attribute__((ext_vector_type(4)));

#define ASYNC_COPY16(gsrc, ldst)                                              \
  __builtin_amdgcn_global_load_lds(                                           \
      (const __attribute__((address_space(1))) void*)(gsrc),                  \
      (__attribute__((address_space(3))) void*)(ldst), 16, 0, 0)

// scale*log2e = (1/sqrt(192)) * 1.4426950408889634
#define QSCALE 0.1041177003f

// ---------------- fp32 -> bf16 convert (vectorized) --------------------------
__global__ void conv_bf16(const float* __restrict__ in, bf16_t* __restrict__ out,
                          int n4) {
  int i = blockIdx.x * 256 + threadIdx.x;
  if (i >= n4) return;
  float4 v = ((const float4*)in)[i];
  bf16x4_t o = {(bf16_t)v.x, (bf16_t)v.y, (bf16_t)v.z, (bf16_t)v.w};
  ((bf16x4_t*)out)[i] = o;
}

// ---------------- transpose+convert weights: [K][N] f32 -> [N][K] bf16 -------
__global__ __launch_bounds__(256) void transw(const float* __restrict__ in,
                                              bf16_t* __restrict__ out, int K,
                                              int N) {
  __shared__ float t[32][33];
  int k0 = blockIdx.y * 32, n0 = blockIdx.x * 32;
  int tx = threadIdx.x, ty = threadIdx.y;
#pragma unroll
  for (int i = 0; i < 4; i++)
    t[ty + i * 8][tx] = in[(size_t)(k0 + ty + i * 8) * N + n0 + tx];
  __syncthreads();
#pragma unroll
  for (int i = 0; i < 4; i++)
    out[(size_t)(n0 + ty + i * 8) * K + k0 + tx] = (bf16_t)t[tx][ty + i * 8];
}

// ---------------- bf16 MFMA GEMM: C = A(MxK) @ Bt(NxK)^T ---------------------
// MODE 0: C[row*N+col] = val
// MODE 1: Kp layout: out[((b*16+h)*2048+s)*192 + d], h=col>>7, d=col&127
// MODE 2: Qp layout: out[((b*16+h)*2048+s)*192 + f]*QSCALE, h=col/192, f=col%192
// MODE 3: Vt layout: out[((b*16+h)*128 + d)*2048 + s],  h=col>>7, d=col&127
template <typename OT, int MODE>
__global__ __launch_bounds__(256) void gemm_bt(const bf16_t* __restrict__ A,
                                               const bf16_t* __restrict__ Bt,
                                               OT* __restrict__ C, int M, int N,
                                               int K) {
  __shared__ bf16_t Asm[128 * 32];
  __shared__ bf16_t Bsm[128 * 32];
  int tid = threadIdx.x;
  int w = tid >> 6, lane = tid & 63;
  int lrow = lane & 15, lgrp = lane >> 4;
  int wr = w >> 1, wc = w & 1;
  int bm = blockIdx.y * 128, bn = blockIdx.x * 128;

  const bf16_t* Ab = A + (size_t)bm * K;
  const bf16_t* Bb = Bt + (size_t)bn * K;

  int srow = (w << 5) + (lane >> 2);
  int schunk = lane & 3;

  int ra[4], rb[4];
#pragma unroll
  for (int m = 0; m < 4; m++) {
    int rowA = wr * 64 + m * 16 + lrow;
    ra[m] = rowA * 64 + ((lgrp * 16) ^ (((rowA >> 1) & 3) << 4));
    int rowB = wc * 64 + m * 16 + lrow;
    rb[m] = rowB * 64 + ((lgrp * 16) ^ (((rowB >> 1) & 3) << 4));
  }

  f32x4 acc[4][4] = {};

  for (int k0 = 0; k0 < K; k0 += 32) {
#pragma unroll
    for (int j = 0; j < 2; j++) {
      int row = srow + j * 16;
      int cs = schunk ^ ((row >> 1) & 3);
      ASYNC_COPY16(Ab + (size_t)row * K + k0 + cs * 8,
                   (char*)Asm + (w << 11) + (j << 10));
      ASYNC_COPY16(Bb + (size_t)row * K + k0 + cs * 8,
                   (char*)Bsm + (w << 11) + (j << 10));
    }
    __syncthreads();
    bf16x8 af[4], bfr[4];
#pragma unroll
    for (int m = 0; m < 4; m++) {
      af[m] = *(const bf16x8*)((const char*)Asm + ra[m]);
      bfr[m] = *(const bf16x8*)((const char*)Bsm + rb[m]);
    }
#pragma unroll
    for (int m = 0; m < 4; m++)
#pragma unroll
      for (int n = 0; n < 4; n++)
        acc[m][n] =
            __builtin_amdgcn_mfma_f32_16x16x32_bf16(af[m], bfr[n], acc[m][n], 0, 0, 0);
    __syncthreads();
  }

#pragma unroll
  for (int m = 0; m < 4; m++)
#pragma unroll
    for (int n = 0; n < 4; n++)
#pragma unroll
      for (int j = 0; j < 4; j++) {
        int row = bm + wr * 64 + m * 16 + lgrp * 4 + j;
        int col = bn + wc * 64 + n * 16 + lrow;
        float val = acc[m][n][j];
        if (MODE == 0) {
          C[(size_t)row * N + col] = (OT)val;
        } else if (MODE == 1) {
          int b = row >> 11, s = row & (S_ - 1);
          int h = col >> 7, d = col & 127;
          ((bf16_t*)C)[((size_t)((b << 4) + h) * S_ + s) * 192 + d] = (bf16_t)val;
        } else if (MODE == 2) {
          int b = row >> 11, s = row & (S_ - 1);
          unsigned h = (unsigned)col / 192u, f = (unsigned)col % 192u;
          ((bf16_t*)C)[((size_t)((b << 4) + h) * S_ + s) * 192 + f] =
              (bf16_t)(val * QSCALE);
        } else {
          int b = row >> 11, s = row & (S_ - 1);
          int h = col >> 7, d = col & 127;
          ((bf16_t*)C)[((size_t)((b << 4) + h) * 128 + d) * S_ + s] = (bf16_t)val;
        }
      }
}

// ---------------- fp32 GEMM (kept for the tiny w_ukrope projection) ----------
__global__ __launch_bounds__(256) void gemm_f32(
    const float* __restrict__ A, const float* __restrict__ Bm,
    float* __restrict__ C, int M, int N, int K) {
  const int BK = 16;
  __shared__ float As[16][65];
  __shared__ float Bs[16][65];
  int tid = threadIdx.x;
  int bm = blockIdx.y * 64, bn = blockIdx.x * 64;
  int tcol = tid & 15, trow = tid >> 4;
  float acc[4][4] = {};
  for (int k0 = 0; k0 < K; k0 += BK) {
#pragma unroll
    for (int i = 0; i < 4; i++) {
      int r = (tid >> 4) + i * 16, c = tid & 15;
      As[c][r] = A[(size_t)(bm + r) * K + k0 + c];
    }
#pragma unroll
    for (int i = 0; i < 4; i++) {
      int r = (tid >> 6) + i * 4, c = tid & 63;
      Bs[r][c] = Bm[(size_t)(k0 + r) * N + bn + c];
    }
    __syncthreads();
#pragma unroll
    for (int kk = 0; kk < BK; kk++) {
      float a[4], b[4];
#pragma unroll
      for (int i = 0; i < 4; i++) a[i] = As[kk][trow * 4 + i];
#pragma unroll
      for (int j = 0; j < 4; j++) b[j] = Bs[kk][tcol * 4 + j];
#pragma unroll
      for (int i = 0; i < 4; i++)
#pragma unroll
        for (int j = 0; j < 4; j++) acc[i][j] = fmaf(a[i], b[j], acc[i][j]);
    }
    __syncthreads();
  }
#pragma unroll
  for (int i = 0; i < 4; i++)
#pragma unroll
    for (int j = 0; j < 4; j++)
      C[(size_t)(bm + trow * 4 + i) * N + bn + tcol * 4 + j] = acc[i][j];
}

// ---------------- rmsnorm over bf16 rows of length 512, in place -------------
__global__ __launch_bounds__(256) void rmsnorm512_b(bf16_t* __restrict__ x,
                                                    const float* __restrict__ g) {
  int row = blockIdx.x;
  bf16_t* p = x + (size_t)row * 512;
  int t = threadIdx.x;
  float v0 = (float)p[t], v1 = (float)p[t + 256];
  __shared__ float red[256];
  red[t] = v0 * v0 + v1 * v1;
  __syncthreads();
  for (int s = 128; s > 0; s >>= 1) {
    if (t < s) red[t] += red[t + s];
    __syncthreads();
  }
  float r = rsqrtf(red[0] / 512.f + 1e-6f);
  p[t] = (bf16_t)(v0 * r * g[t]);
  p[t + 256] = (bf16_t)(v1 * r * g[t + 256]);
}

// ---------------- rope on kr fp32 rows x 64, in place ------------------------
__global__ void rope64(float* __restrict__ x, int rows) {
  int i = blockIdx.x * blockDim.x + threadIdx.x;
  if (i >= rows * 32) return;
  int r = i >> 5, j = i & 31;
  int s = r & (S_ - 1);
  float freq = powf(10000.f, -(float)(2 * j) / 64.f);
  float ang = (float)s * freq;
  float c = cosf(ang), sn = sinf(ang);
  size_t base = (size_t)r * 64 + 2 * j;
  float x0 = x[base], x1 = x[base + 1];
  x[base] = x0 * c - x1 * sn;
  x[base + 1] = x1 * c + x0 * sn;
}

// ---------------- rope on Qp rope-section in place (bf16) --------------------
__global__ void rope_qp(bf16_t* __restrict__ Qp) {
  int i = blockIdx.x * 256 + threadIdx.x;  // 32*2048*32 pairs
  if (i >= 32 * S_ * 32) return;
  int j = i & 31;
  int s = (i >> 5) & (S_ - 1);
  int bh = i >> 16;
  float freq = powf(10000.f, -(float)(2 * j) / 64.f);
  float ang = (float)s * freq;
  float c = cosf(ang), sn = sinf(ang);
  size_t base = ((size_t)bh * S_ + s) * 192 + 128 + 2 * j;
  float x0 = (float)Qp[base], x1 = (float)Qp[base + 1];
  Qp[base] = (bf16_t)(x0 * c - x1 * sn);
  Qp[base + 1] = (bf16_t)(x1 * c + x0 * sn);
}

// ---------------- broadcast rope'd kr into Kp rope section ------------------
__global__ void pack_kr(const float* __restrict__ kr, bf16_t* __restrict__ Kp) {
  int i = blockIdx.x * 256 + threadIdx.x;  // 32*2048*64
  if (i >= 32 * S_ * 64) return;
  int f = i & 63;
  int s = (i >> 6) & (S_ - 1);
  int bh = i >> 17;
  int b = bh >> 4;
  Kp[((size_t)bh * S_ + s) * 192 + 128 + f] =
      (bf16_t)kr[((size_t)(b * S_ + s)) * 64 + f];
}

// ---------------- flash attention v2: LDS-staged K/V, balanced pairs ---------
// grid: 512 blocks x 256 threads (4 waves). Block -> (pair, bh) with XCD
// grouping: bid = (bh&7) + 8*(pair + 16*(bh>>3)). Each block does q-tiles
// {31-pair, pair}: exactly 33 k-tiles of work -> perfect balance.
#define KROW 400   // K LDS row stride bytes (384 data + 16 pad)
#define VROW 144   // V LDS row stride bytes (128 data + 16 pad)
__global__ __launch_bounds__(256) void flash_attn2(
    const bf16_t* __restrict__ Qp,  // [BH][S][192], pre-scaled
    const bf16_t* __restrict__ Kp,  // [BH][S][192]
    const bf16_t* __restrict__ Vt,  // [BH][128][S]
    bf16_t* __restrict__ o) {       // [B*S][2048] bf16
  __shared__ alignas(16) char kls[64 * KROW];
  __shared__ alignas(16) char vls[128 * VROW];
  __shared__ alignas(16) bf16_t psh[4][16 * 64];

  int bid = blockIdx.x;
  int rest = bid >> 3;
  int pair = rest & 15;
  int bh = (bid & 7) + ((rest >> 4) << 3);
  int b = bh >> 4;

  int tid = threadIdx.x;
  int w = tid >> 6;
  int lane = tid & 63;
  int lrow = lane & 15;
  int lgrp = lane >> 4;
  bf16_t* pw = &psh[w][0];

  const char* Kbh = (const char*)(Kp + (size_t)bh * S_ * 192);
  const char* Vbh = (const char*)(Vt + (size_t)bh * 128 * S_);

  int4 kr[6], vr[4];
  auto stage_load = [&](int kt) {
    const char* kb = Kbh + (size_t)kt * (64 * 384);
#pragma unroll
    for (int r = 0; r < 6; r++) kr[r] = *(const int4*)(kb + (tid + r * 256) * 16);
    const char* vb2 = Vbh + (size_t)kt * 128;
#pragma unroll
    for (int r = 0; r < 4; r++) {
      int c = tid + r * 256;
      vr[r] = *(const int4*)(vb2 + (size_t)(c >> 3) * 4096 + (c & 7) * 16);
    }
  };
  auto stage_write = [&]() {
#pragma unroll
    for (int r = 0; r < 6; r++) {
      int c = tid + r * 256;
      int row = c / 24, pos = c - row * 24;
      *(int4*)(kls + row * KROW + pos * 16) = kr[r];
    }
#pragma unroll
    for (int r = 0; r < 4; r++) {
      int c = tid + r * 256;
      *(int4*)(vls + (c >> 3) * VROW + (c & 7) * 16) = vr[r];
    }
  };

#pragma unroll 1
  for (int half = 0; half < 2; half++) {
    const int qt = half ? pair : (31 - pair);
    const int qb = qt * 64 + w * 16;
    const bf16_t* Qb = Qp + ((size_t)bh * S_ + qb) * 192;

    bf16x8 qf[6];
#pragma unroll
    for (int ks = 0; ks < 6; ks++)
      qf[ks] = *(const bf16x8*)(Qb + (size_t)lrow * 192 + ks * 32 + lgrp * 8);

    f32x4 acc[8];
#pragma unroll
    for (int i = 0; i < 8; i++) acc[i] = f32x4{0.f, 0.f, 0.f, 0.f};
    float mrow[4], lsum[4];
#pragma unroll
    for (int r = 0; r < 4; r++) { mrow[r] = -1e30f; lsum[r] = 0.f; }

    stage_load(0);
#pragma unroll 1
    for (int kt = 0; kt <= qt; kt++) {
      __syncthreads();  // all waves done computing previous tile
      stage_write();
      __syncthreads();  // staged data visible
      if (kt < qt) stage_load(kt + 1);  // prefetch (in flight during compute)

      // ---- QK^T from LDS ----
      f32x4 sc[4];
#pragma unroll
      for (int cb = 0; cb < 4; cb++) {
        f32x4 s = f32x4{0.f, 0.f, 0.f, 0.f};
        const char* kp = kls + (cb * 16 + lrow) * KROW + lgrp * 16;
#pragma unroll
        for (int ks = 0; ks < 6; ks++) {
          bf16x8 kf = *(const bf16x8*)(kp + ks * 64);
          s = __builtin_amdgcn_mfma_f32_16x16x32_bf16(qf[ks], kf, s, 0, 0, 0);
        }
        sc[cb] = s;
      }
      if (kt == qt) {
#pragma unroll
        for (int cb = 0; cb < 4; cb++)
#pragma unroll
          for (int r = 0; r < 4; r++) {
            int col = kt * 64 + cb * 16 + lrow;
            int row = qb + lgrp * 4 + r;
            if (col > row) sc[cb][r] = -1e30f;
          }
      }
      // ---- online softmax (log2 domain) ----
#pragma unroll
      for (int r = 0; r < 4; r++) {
        float v = fmaxf(fmaxf(sc[0][r], sc[1][r]), fmaxf(sc[2][r], sc[3][r]));
        v = fmaxf(v, __shfl_xor(v, 1));
        v = fmaxf(v, __shfl_xor(v, 2));
        v = fmaxf(v, __shfl_xor(v, 4));
        v = fmaxf(v, __shfl_xor(v, 8));
        float mn = fmaxf(mrow[r], v);
        float alpha = exp2f(mrow[r] - mn);
        mrow[r] = mn;
        lsum[r] *= alpha;
#pragma unroll
        for (int cb = 0; cb < 8; cb++) acc[cb][r] *= alpha;
        float ps = 0.f;
#pragma unroll
        for (int cb = 0; cb < 4; cb++) {
          float e = exp2f(sc[cb][r] - mn);
          sc[cb][r] = e;
          ps += e;
        }
        ps += __shfl_xor(ps, 1);
        ps += __shfl_xor(ps, 2);
        ps += __shfl_xor(ps, 4);
        ps += __shfl_xor(ps, 8);
        lsum[r] += ps;
      }
      // ---- stage P (per-wave LDS, no block barrier needed) ----
#pragma unroll
      for (int r = 0; r < 4; r++) {
        int row = lgrp * 4 + r;
#pragma unroll
        for (int cb = 0; cb < 4; cb++) {
          int byte = (row * 128 + (cb * 16 + lrow) * 2) ^ ((row & 7) << 4);
          *(bf16_t*)((char*)pw + byte) = (bf16_t)sc[cb][r];
        }
      }
      bf16x8 pa[2];
#pragma unroll
      for (int ks = 0; ks < 2; ks++) {
        int byte = (lrow * 128 + ks * 64 + lgrp * 16) ^ ((lrow & 7) << 4);
        pa[ks] = *(const bf16x8*)((char*)pw + byte);
      }
      // ---- O += P @ V from LDS ----
#pragma unroll
      for (int cbv = 0; cbv < 8; cbv++) {
        const char* vp = vls + (cbv * 16 + lrow) * VROW + lgrp * 16;
        f32x4 a = acc[cbv];
#pragma unroll
        for (int ks = 0; ks < 2; ks++) {
          bf16x8 vf = *(const bf16x8*)(vp + ks * 64);
          a = __builtin_amdgcn_mfma_f32_16x16x32_bf16(pa[ks], vf, a, 0, 0, 0);
        }
        acc[cbv] = a;
      }
    }
    // ---- normalize + store ----
#pragma unroll
    for (int r = 0; r < 4; r++) {
      float inv = 1.f / lsum[r];
      int row = qb + lgrp * 4 + r;
      bf16_t* op = o + (size_t)(b * S_ + row) * 2048 + (bh & 15) * 128;
#pragma unroll
      for (int cbv = 0; cbv < 8; cbv++)
        op[cbv * 16 + lrow] = (bf16_t)(acc[cbv][r] * inv);
    }
  }
}

extern "C" void kernel_launch(void* const* d_in, const int* in_sizes, int n_in,
                              void* d_out, int out_size, void* d_ws, size_t ws_size,
                              hipStream_t stream) {
  const float* x        = (const float*)d_in[0];
  const float* w_dq     = (const float*)d_in[1];
  const float* g_q      = (const float*)d_in[2];
  const float* w_uq     = (const float*)d_in[3];
  const float* w_dkv    = (const float*)d_in[4];
  const float* g_kv     = (const float*)d_in[5];
  const float* w_ukrope = (const float*)d_in[6];
  const float* w_uv     = (const float*)d_in[7];
  const float* w_uknope = (const float*)d_in[8];
  const float* w_o      = (const float*)d_in[9];
  float* out = (float*)d_out;

  const int M = 4096;
  float* kr = (float*)d_ws;                      // 4096*64 f32
  bf16_t* wb = (bf16_t*)(kr + (size_t)M * 64);   // bf16 arena
  size_t off = 0;
  bf16_t* xb   = wb + off; off += (size_t)M * 2048;   // reused as ao
  bf16_t* y_q  = wb + off; off += (size_t)M * 512;
  bf16_t* y_kv = wb + off; off += (size_t)M * 512;
  bf16_t* dq_t = wb + off; off += (size_t)512 * 2048;
  bf16_t* dkv_t= wb + off; off += (size_t)512 * 2048;
  bf16_t* uq_t = wb + off; off += (size_t)3072 * 512;
  bf16_t* ukn_t= wb + off; off += (size_t)2048 * 512;
  bf16_t* uv_t = wb + off; off += (size_t)2048 * 512;
  bf16_t* o_t  = wb + off; off += (size_t)2048 * 2048;
  bf16_t* Qp   = wb + off; off += (size_t)32 * S_ * 192;
  bf16_t* Kp   = wb + off; off += (size_t)32 * S_ * 192;
  bf16_t* Vt   = wb + off; off += (size_t)32 * 128 * S_;
  bf16_t* ao = xb;  // xb dead after down-projections

  dim3 blk(256);
  dim3 tb(32, 8);
  conv_bf16<<<(M * 2048 / 4 + 255) / 256, blk, 0, stream>>>(x, xb, M * 2048 / 4);
  transw<<<dim3(512 / 32, 2048 / 32), tb, 0, stream>>>(w_dq, dq_t, 2048, 512);
  transw<<<dim3(512 / 32, 2048 / 32), tb, 0, stream>>>(w_dkv, dkv_t, 2048, 512);
  transw<<<dim3(3072 / 32, 512 / 32), tb, 0, stream>>>(w_uq, uq_t, 512, 3072);
  transw<<<dim3(2048 / 32, 512 / 32), tb, 0, stream>>>(w_uknope, ukn_t, 512, 2048);
  transw<<<dim3(2048 / 32, 512 / 32), tb, 0, stream>>>(w_uv, uv_t, 512, 2048);
  transw<<<dim3(2048 / 32, 2048 / 32), tb, 0, stream>>>(w_o, o_t, 2048, 2048);
  gemm_f32<<<dim3(1, M / 64), blk, 0, stream>>>(x, w_ukrope, kr, M, 64, 2048);
  // down-projections
  gemm_bt<bf16_t, 0><<<dim3(4, 32), blk, 0, stream>>>(xb, dq_t, y_q, M, 512, 2048);
  gemm_bt<bf16_t, 0><<<dim3(4, 32), blk, 0, stream>>>(xb, dkv_t, y_kv, M, 512, 2048);
  rmsnorm512_b<<<M, blk, 0, stream>>>(y_q, g_q);
  rmsnorm512_b<<<M, blk, 0, stream>>>(y_kv, g_kv);
  // up-projections fused into attention layouts
  gemm_bt<bf16_t, 2><<<dim3(24, 32), blk, 0, stream>>>(y_q, uq_t, Qp, M, 3072, 512);
  gemm_bt<bf16_t, 1><<<dim3(16, 32), blk, 0, stream>>>(y_kv, ukn_t, Kp, M, 2048, 512);
  gemm_bt<bf16_t, 3><<<dim3(16, 32), blk, 0, stream>>>(y_kv, uv_t, Vt, M, 2048, 512);
  // rope + remaining packs
  rope64<<<(M * 32 + 255) / 256, blk, 0, stream>>>(kr, M);
  rope_qp<<<(32 * S_ * 32 + 255) / 256, blk, 0, stream>>>(Qp);
  pack_kr<<<(32 * S_ * 64 + 255) / 256, blk, 0, stream>>>(kr, Kp);
  // flash attention (pair-balanced, LDS-staged)
  flash_attn2<<<512, blk, 0, stream>>>(Qp, Kp, Vt, ao);
  // output projection
  gemm_bt<float, 0><<<dim3(16, 32), blk, 0, stream>>>(ao, o_t, out, M, 2048, 2048);
}

// Round 7
// 498.309 us; speedup vs baseline: 18.3336x; 1.2401x over previous
//
#include <hip/hip_runtime.h>
#include <hip/hip_bf16.h>

// MLA: bf16 MFMA GEMMs + gload_lds-staged, pair-balanced bf16 MFMA flash attn.
// B=2, S=2048, E=2048, C=512, H=16, Dn=128, Dr=64.

#define S_ 2048
#define H_ 16

typedef __bf16 bf16_t;
typedef __bf16 bf16x8 __attribute__((ext_vector_type(8)));
typedef __bf16 bf16x4_t __attribute__((ext_vector_type(4)));
typedef float f32x4 __attribute__((ext_vector_type(4)));

#define ASYNC_COPY16(gsrc, ldst)                                              \
  __builtin_amdgcn_global_load_lds(                                           \
      (const __attribute__((address_space(1))) void*)(gsrc),                  \
      (__attribute__((address_space(3))) void*)(ldst), 16, 0, 0)

// scale*log2e = (1/sqrt(192)) * 1.4426950408889634
#define QSCALE 0.1041177003f

// ---------------- fp32 -> bf16 convert (vectorized) --------------------------
__global__ void conv_bf16(const float* __restrict__ in, bf16_t* __restrict__ out,
                          int n4) {
  int i = blockIdx.x * 256 + threadIdx.x;
  if (i >= n4) return;
  float4 v = ((const float4*)in)[i];
  bf16x4_t o = {(bf16_t)v.x, (bf16_t)v.y, (bf16_t)v.z, (bf16_t)v.w};
  ((bf16x4_t*)out)[i] = o;
}

// ---------------- transpose+convert weights: [K][N] f32 -> [N][K] bf16 -------
__global__ __launch_bounds__(256) void transw(const float* __restrict__ in,
                                              bf16_t* __restrict__ out, int K,
                                              int N) {
  __shared__ float t[32][33];
  int k0 = blockIdx.y * 32, n0 = blockIdx.x * 32;
  int tx = threadIdx.x, ty = threadIdx.y;
#pragma unroll
  for (int i = 0; i < 4; i++)
    t[ty + i * 8][tx] = in[(size_t)(k0 + ty + i * 8) * N + n0 + tx];
  __syncthreads();
#pragma unroll
  for (int i = 0; i < 4; i++)
    out[(size_t)(n0 + ty + i * 8) * K + k0 + tx] = (bf16_t)t[tx][ty + i * 8];
}

// ---------------- bf16 MFMA GEMM: C = A(MxK) @ Bt(NxK)^T ---------------------
// MODE 0: C[row*N+col] = val
// MODE 1: Kp layout: out[((b*16+h)*2048+s)*192 + d], h=col>>7, d=col&127
// MODE 2: Qp layout: out[((b*16+h)*2048+s)*192 + f]*QSCALE, h=col/192, f=col%192
// MODE 3: Vt layout: out[((b*16+h)*128 + d)*2048 + s],  h=col>>7, d=col&127
template <typename OT, int MODE>
__global__ __launch_bounds__(256) void gemm_bt(const bf16_t* __restrict__ A,
                                               const bf16_t* __restrict__ Bt,
                                               OT* __restrict__ C, int M, int N,
                                               int K) {
  __shared__ bf16_t Asm[128 * 32];
  __shared__ bf16_t Bsm[128 * 32];
  int tid = threadIdx.x;
  int w = tid >> 6, lane = tid & 63;
  int lrow = lane & 15, lgrp = lane >> 4;
  int wr = w >> 1, wc = w & 1;
  int bm = blockIdx.y * 128, bn = blockIdx.x * 128;

  const bf16_t* Ab = A + (size_t)bm * K;
  const bf16_t* Bb = Bt + (size_t)bn * K;

  int srow = (w << 5) + (lane >> 2);
  int schunk = lane & 3;

  int ra[4], rb[4];
#pragma unroll
  for (int m = 0; m < 4; m++) {
    int rowA = wr * 64 + m * 16 + lrow;
    ra[m] = rowA * 64 + ((lgrp * 16) ^ (((rowA >> 1) & 3) << 4));
    int rowB = wc * 64 + m * 16 + lrow;
    rb[m] = rowB * 64 + ((lgrp * 16) ^ (((rowB >> 1) & 3) << 4));
  }

  f32x4 acc[4][4] = {};

  for (int k0 = 0; k0 < K; k0 += 32) {
#pragma unroll
    for (int j = 0; j < 2; j++) {
      int row = srow + j * 16;
      int cs = schunk ^ ((row >> 1) & 3);
      ASYNC_COPY16(Ab + (size_t)row * K + k0 + cs * 8,
                   (char*)Asm + (w << 11) + (j << 10));
      ASYNC_COPY16(Bb + (size_t)row * K + k0 + cs * 8,
                   (char*)Bsm + (w << 11) + (j << 10));
    }
    __syncthreads();
    bf16x8 af[4], bfr[4];
#pragma unroll
    for (int m = 0; m < 4; m++) {
      af[m] = *(const bf16x8*)((const char*)Asm + ra[m]);
      bfr[m] = *(const bf16x8*)((const char*)Bsm + rb[m]);
    }
#pragma unroll
    for (int m = 0; m < 4; m++)
#pragma unroll
      for (int n = 0; n < 4; n++)
        acc[m][n] =
            __builtin_amdgcn_mfma_f32_16x16x32_bf16(af[m], bfr[n], acc[m][n], 0, 0, 0);
    __syncthreads();
  }

#pragma unroll
  for (int m = 0; m < 4; m++)
#pragma unroll
    for (int n = 0; n < 4; n++)
#pragma unroll
      for (int j = 0; j < 4; j++) {
        int row = bm + wr * 64 + m * 16 + lgrp * 4 + j;
        int col = bn + wc * 64 + n * 16 + lrow;
        float val = acc[m][n][j];
        if (MODE == 0) {
          C[(size_t)row * N + col] = (OT)val;
        } else if (MODE == 1) {
          int b = row >> 11, s = row & (S_ - 1);
          int h = col >> 7, d = col & 127;
          ((bf16_t*)C)[((size_t)((b << 4) + h) * S_ + s) * 192 + d] = (bf16_t)val;
        } else if (MODE == 2) {
          int b = row >> 11, s = row & (S_ - 1);
          unsigned h = (unsigned)col / 192u, f = (unsigned)col % 192u;
          ((bf16_t*)C)[((size_t)((b << 4) + h) * S_ + s) * 192 + f] =
              (bf16_t)(val * QSCALE);
        } else {
          int b = row >> 11, s = row & (S_ - 1);
          int h = col >> 7, d = col & 127;
          ((bf16_t*)C)[((size_t)((b << 4) + h) * 128 + d) * S_ + s] = (bf16_t)val;
        }
      }
}

// ---------------- fp32 GEMM (kept for the tiny w_ukrope projection) ----------
__global__ __launch_bounds__(256) void gemm_f32(
    const float* __restrict__ A, const float* __restrict__ Bm,
    float* __restrict__ C, int M, int N, int K) {
  const int BK = 16;
  __shared__ float As[16][65];
  __shared__ float Bs[16][65];
  int tid = threadIdx.x;
  int bm = blockIdx.y * 64, bn = blockIdx.x * 64;
  int tcol = tid & 15, trow = tid >> 4;
  float acc[4][4] = {};
  for (int k0 = 0; k0 < K; k0 += BK) {
#pragma unroll
    for (int i = 0; i < 4; i++) {
      int r = (tid >> 4) + i * 16, c = tid & 15;
      As[c][r] = A[(size_t)(bm + r) * K + k0 + c];
    }
#pragma unroll
    for (int i = 0; i < 4; i++) {
      int r = (tid >> 6) + i * 4, c = tid & 63;
      Bs[r][c] = Bm[(size_t)(k0 + r) * N + bn + c];
    }
    __syncthreads();
#pragma unroll
    for (int kk = 0; kk < BK; kk++) {
      float a[4], b[4];
#pragma unroll
      for (int i = 0; i < 4; i++) a[i] = As[kk][trow * 4 + i];
#pragma unroll
      for (int j = 0; j < 4; j++) b[j] = Bs[kk][tcol * 4 + j];
#pragma unroll
      for (int i = 0; i < 4; i++)
#pragma unroll
        for (int j = 0; j < 4; j++) acc[i][j] = fmaf(a[i], b[j], acc[i][j]);
    }
    __syncthreads();
  }
#pragma unroll
  for (int i = 0; i < 4; i++)
#pragma unroll
    for (int j = 0; j < 4; j++)
      C[(size_t)(bm + trow * 4 + i) * N + bn + tcol * 4 + j] = acc[i][j];
}

// ---------------- rmsnorm over bf16 rows of length 512, in place -------------
__global__ __launch_bounds__(256) void rmsnorm512_b(bf16_t* __restrict__ x,
                                                    const float* __restrict__ g) {
  int row = blockIdx.x;
  bf16_t* p = x + (size_t)row * 512;
  int t = threadIdx.x;
  float v0 = (float)p[t], v1 = (float)p[t + 256];
  __shared__ float red[256];
  red[t] = v0 * v0 + v1 * v1;
  __syncthreads();
  for (int s = 128; s > 0; s >>= 1) {
    if (t < s) red[t] += red[t + s];
    __syncthreads();
  }
  float r = rsqrtf(red[0] / 512.f + 1e-6f);
  p[t] = (bf16_t)(v0 * r * g[t]);
  p[t + 256] = (bf16_t)(v1 * r * g[t + 256]);
}

// ---------------- rope on kr fp32 rows x 64, in place ------------------------
__global__ void rope64(float* __restrict__ x, int rows) {
  int i = blockIdx.x * blockDim.x + threadIdx.x;
  if (i >= rows * 32) return;
  int r = i >> 5, j = i & 31;
  int s = r & (S_ - 1);
  float freq = powf(10000.f, -(float)(2 * j) / 64.f);
  float ang = (float)s * freq;
  float c = cosf(ang), sn = sinf(ang);
  size_t base = (size_t)r * 64 + 2 * j;
  float x0 = x[base], x1 = x[base + 1];
  x[base] = x0 * c - x1 * sn;
  x[base + 1] = x1 * c + x0 * sn;
}

// ---------------- rope on Qp rope-section in place (bf16) --------------------
__global__ void rope_qp(bf16_t* __restrict__ Qp) {
  int i = blockIdx.x * 256 + threadIdx.x;  // 32*2048*32 pairs
  if (i >= 32 * S_ * 32) return;
  int j = i & 31;
  int s = (i >> 5) & (S_ - 1);
  int bh = i >> 16;
  float freq = powf(10000.f, -(float)(2 * j) / 64.f);
  float ang = (float)s * freq;
  float c = cosf(ang), sn = sinf(ang);
  size_t base = ((size_t)bh * S_ + s) * 192 + 128 + 2 * j;
  float x0 = (float)Qp[base], x1 = (float)Qp[base + 1];
  Qp[base] = (bf16_t)(x0 * c - x1 * sn);
  Qp[base + 1] = (bf16_t)(x1 * c + x0 * sn);
}

// ---------------- broadcast rope'd kr into Kp rope section ------------------
__global__ void pack_kr(const float* __restrict__ kr, bf16_t* __restrict__ Kp) {
  int i = blockIdx.x * 256 + threadIdx.x;  // 32*2048*64
  if (i >= 32 * S_ * 64) return;
  int f = i & 63;
  int s = (i >> 6) & (S_ - 1);
  int bh = i >> 17;
  int b = bh >> 4;
  Kp[((size_t)bh * S_ + s) * 192 + 128 + f] =
      (bf16_t)kr[((size_t)(b * S_ + s)) * 64 + f];
}

// ---------------- flash attention v3: global_load_lds staging ----------------
// grid: 512 blocks x 256 threads (4 waves). Block -> (pair, bh) with XCD
// grouping. Each block does q-tiles {31-pair, pair}: exactly 33 k-tiles.
// K tile: 64 rows x 384 B linear LDS; V tile: 128 rows x 128 B linear LDS.
// Bank swizzle via per-lane GLOBAL source: LDS[row][p] = G[row][p ^ (row&7)],
// reader XORs the same involution -> stride-384/128 row reads are bank-flat.
__global__ __launch_bounds__(256) void flash_attn3(
    const bf16_t* __restrict__ Qp,  // [BH][S][192], pre-scaled
    const bf16_t* __restrict__ Kp,  // [BH][S][192]
    const bf16_t* __restrict__ Vt,  // [BH][128][S]
    bf16_t* __restrict__ o) {       // [B*S][2048] bf16
  __shared__ alignas(16) char kls[64 * 384];   // 24 KB
  __shared__ alignas(16) char vls[128 * 128];  // 16 KB
  __shared__ alignas(16) bf16_t psh[4][16 * 64];  // 8 KB

  int bid = blockIdx.x;
  int rest = bid >> 3;
  int pair = rest & 15;
  int bh = (bid & 7) + ((rest >> 4) << 3);
  int b = bh >> 4;

  int tid = threadIdx.x;
  int w = tid >> 6;
  int lane = tid & 63;
  int lrow = lane & 15;
  int lgrp = lane >> 4;
  bf16_t* pw = &psh[w][0];

  const char* Kbh = (const char*)(Kp + (size_t)bh * S_ * 192);
  const char* Vbh = (const char*)(Vt + (size_t)bh * 128 * S_);

  // staging source offsets (fixed per thread)
  int ksrc[6], vsrc[4];
#pragma unroll
  for (int r = 0; r < 6; r++) {
    int c = tid + r * 256;          // chunk id 0..1535
    int row = c / 24, pos = c - row * 24;
    ksrc[r] = row * 384 + ((pos ^ (row & 7)) << 4);
  }
#pragma unroll
  for (int r = 0; r < 4; r++) {
    int c = tid + r * 256;          // chunk id 0..1023
    int d = c >> 3, pos = c & 7;
    vsrc[r] = d * 4096 + ((pos ^ (d & 7)) << 4);
  }

  // ds_read chunk offsets (XOR the same involution back)
  int kchk[6], vchk[2];
#pragma unroll
  for (int ks = 0; ks < 6; ks++)
    kchk[ks] = (((lgrp + ks * 4) ^ (lrow & 7)) << 4) + lrow * 384;
#pragma unroll
  for (int ks = 0; ks < 2; ks++)
    vchk[ks] = (((lgrp + ks * 4) ^ (lrow & 7)) << 4) + lrow * 128;

#pragma unroll 1
  for (int half = 0; half < 2; half++) {
    const int qt = half ? pair : (31 - pair);
    const int qb = qt * 64 + w * 16;
    const bf16_t* Qb = Qp + ((size_t)bh * S_ + qb) * 192;

    bf16x8 qf[6];
#pragma unroll
    for (int ks = 0; ks < 6; ks++)
      qf[ks] = *(const bf16x8*)(Qb + (size_t)lrow * 192 + ks * 32 + lgrp * 8);

    f32x4 acc[8];
#pragma unroll
    for (int i = 0; i < 8; i++) acc[i] = f32x4{0.f, 0.f, 0.f, 0.f};
    float mrow[4], lsum[4];
#pragma unroll
    for (int r = 0; r < 4; r++) { mrow[r] = -1e30f; lsum[r] = 0.f; }

#pragma unroll 1
    for (int kt = 0; kt <= qt; kt++) {
      __syncthreads();  // all waves done reading previous tile
      {
        const char* kb = Kbh + (size_t)kt * (64 * 384);
#pragma unroll
        for (int r = 0; r < 6; r++)
          ASYNC_COPY16(kb + ksrc[r], kls + (tid + r * 256) * 16);
        const char* vb2 = Vbh + (size_t)kt * 128;
#pragma unroll
        for (int r = 0; r < 4; r++)
          ASYNC_COPY16(vb2 + vsrc[r], vls + (tid + r * 256) * 16);
      }
      __syncthreads();  // staged data drained & visible

      // ---- QK^T from LDS ----
      f32x4 sc[4];
#pragma unroll
      for (int cb = 0; cb < 4; cb++) {
        f32x4 s = f32x4{0.f, 0.f, 0.f, 0.f};
        const char* kp = kls + cb * 6144;
#pragma unroll
        for (int ks = 0; ks < 6; ks++) {
          bf16x8 kf = *(const bf16x8*)(kp + kchk[ks]);
          s = __builtin_amdgcn_mfma_f32_16x16x32_bf16(qf[ks], kf, s, 0, 0, 0);
        }
        sc[cb] = s;
      }
      if (kt == qt) {
#pragma unroll
        for (int cb = 0; cb < 4; cb++)
#pragma unroll
          for (int r = 0; r < 4; r++) {
            int col = kt * 64 + cb * 16 + lrow;
            int row = qb + lgrp * 4 + r;
            if (col > row) sc[cb][r] = -1e30f;
          }
      }
      // ---- online softmax (log2 domain) ----
#pragma unroll
      for (int r = 0; r < 4; r++) {
        float v = fmaxf(fmaxf(sc[0][r], sc[1][r]), fmaxf(sc[2][r], sc[3][r]));
        v = fmaxf(v, __shfl_xor(v, 1));
        v = fmaxf(v, __shfl_xor(v, 2));
        v = fmaxf(v, __shfl_xor(v, 4));
        v = fmaxf(v, __shfl_xor(v, 8));
        float mn = fmaxf(mrow[r], v);
        float alpha = exp2f(mrow[r] - mn);
        mrow[r] = mn;
        lsum[r] *= alpha;
#pragma unroll
        for (int cb = 0; cb < 8; cb++) acc[cb][r] *= alpha;
        float ps = 0.f;
#pragma unroll
        for (int cb = 0; cb < 4; cb++) {
          float e = exp2f(sc[cb][r] - mn);
          sc[cb][r] = e;
          ps += e;
        }
        ps += __shfl_xor(ps, 1);
        ps += __shfl_xor(ps, 2);
        ps += __shfl_xor(ps, 4);
        ps += __shfl_xor(ps, 8);
        lsum[r] += ps;
      }
      // ---- stage P (per-wave LDS, wave-local) ----
#pragma unroll
      for (int r = 0; r < 4; r++) {
        int row = lgrp * 4 + r;
#pragma unroll
        for (int cb = 0; cb < 4; cb++) {
          int byte = (row * 128 + (cb * 16 + lrow) * 2) ^ ((row & 7) << 4);
          *(bf16_t*)((char*)pw + byte) = (bf16_t)sc[cb][r];
        }
      }
      bf16x8 pa[2];
#pragma unroll
      for (int ks = 0; ks < 2; ks++) {
        int byte = (lrow * 128 + ks * 64 + lgrp * 16) ^ ((lrow & 7) << 4);
        pa[ks] = *(const bf16x8*)((char*)pw + byte);
      }
      // ---- O += P @ V from LDS ----
#pragma unroll
      for (int cbv = 0; cbv < 8; cbv++) {
        const char* vp = vls + cbv * 2048;
        f32x4 a = acc[cbv];
#pragma unroll
        for (int ks = 0; ks < 2; ks++) {
          bf16x8 vf = *(const bf16x8*)(vp + vchk[ks]);
          a = __builtin_amdgcn_mfma_f32_16x16x32_bf16(pa[ks], vf, a, 0, 0, 0);
        }
        acc[cbv] = a;
      }
    }
    // ---- normalize + store ----
#pragma unroll
    for (int r = 0; r < 4; r++) {
      float inv = 1.f / lsum[r];
      int row = qb + lgrp * 4 + r;
      bf16_t* op = o + (size_t)(b * S_ + row) * 2048 + (bh & 15) * 128;
#pragma unroll
      for (int cbv = 0; cbv < 8; cbv++)
        op[cbv * 16 + lrow] = (bf16_t)(acc[cbv][r] * inv);
    }
  }
}

extern "C" void kernel_launch(void* const* d_in, const int* in_sizes, int n_in,
                              void* d_out, int out_size, void* d_ws, size_t ws_size,
                              hipStream_t stream) {
  const float* x        = (const float*)d_in[0];
  const float* w_dq     = (const float*)d_in[1];
  const float* g_q      = (const float*)d_in[2];
  const float* w_uq     = (const float*)d_in[3];
  const float* w_dkv    = (const float*)d_in[4];
  const float* g_kv     = (const float*)d_in[5];
  const float* w_ukrope = (const float*)d_in[6];
  const float* w_uv     = (const float*)d_in[7];
  const float* w_uknope = (const float*)d_in[8];
  const float* w_o      = (const float*)d_in[9];
  float* out = (float*)d_out;

  const int M = 4096;
  float* kr = (float*)d_ws;                      // 4096*64 f32
  bf16_t* wb = (bf16_t*)(kr + (size_t)M * 64);   // bf16 arena
  size_t off = 0;
  bf16_t* xb   = wb + off; off += (size_t)M * 2048;   // reused as ao
  bf16_t* y_q  = wb + off; off += (size_t)M * 512;
  bf16_t* y_kv = wb + off; off += (size_t)M * 512;
  bf16_t* dq_t = wb + off; off += (size_t)512 * 2048;
  bf16_t* dkv_t= wb + off; off += (size_t)512 * 2048;
  bf16_t* uq_t = wb + off; off += (size_t)3072 * 512;
  bf16_t* ukn_t= wb + off; off += (size_t)2048 * 512;
  bf16_t* uv_t = wb + off; off += (size_t)2048 * 512;
  bf16_t* o_t  = wb + off; off += (size_t)2048 * 2048;
  bf16_t* Qp   = wb + off; off += (size_t)32 * S_ * 192;
  bf16_t* Kp   = wb + off; off += (size_t)32 * S_ * 192;
  bf16_t* Vt   = wb + off; off += (size_t)32 * 128 * S_;
  bf16_t* ao = xb;  // xb dead after down-projections

  dim3 blk(256);
  dim3 tb(32, 8);
  conv_bf16<<<(M * 2048 / 4 + 255) / 256, blk, 0, stream>>>(x, xb, M * 2048 / 4);
  transw<<<dim3(512 / 32, 2048 / 32), tb, 0, stream>>>(w_dq, dq_t, 2048, 512);
  transw<<<dim3(512 / 32, 2048 / 32), tb, 0, stream>>>(w_dkv, dkv_t, 2048, 512);
  transw<<<dim3(3072 / 32, 512 / 32), tb, 0, stream>>>(w_uq, uq_t, 512, 3072);
  transw<<<dim3(2048 / 32, 512 / 32), tb, 0, stream>>>(w_uknope, ukn_t, 512, 2048);
  transw<<<dim3(2048 / 32, 512 / 32), tb, 0, stream>>>(w_uv, uv_t, 512, 2048);
  transw<<<dim3(2048 / 32, 2048 / 32), tb, 0, stream>>>(w_o, o_t, 2048, 2048);
  gemm_f32<<<dim3(1, M / 64), blk, 0, stream>>>(x, w_ukrope, kr, M, 64, 2048);
  // down-projections
  gemm_bt<bf16_t, 0><<<dim3(4, 32), blk, 0, stream>>>(xb, dq_t, y_q, M, 512, 2048);
  gemm_bt<bf16_t, 0><<<dim3(4, 32), blk, 0, stream>>>(xb, dkv_t, y_kv, M, 512, 2048);
  rmsnorm512_b<<<M, blk, 0, stream>>>(y_q, g_q);
  rmsnorm512_b<<<M, blk, 0, stream>>>(y_kv, g_kv);
  // up-projections fused into attention layouts
  gemm_bt<bf16_t, 2><<<dim3(24, 32), blk, 0, stream>>>(y_q, uq_t, Qp, M, 3072, 512);
  gemm_bt<bf16_t, 1><<<dim3(16, 32), blk, 0, stream>>>(y_kv, ukn_t, Kp, M, 2048, 512);
  gemm_bt<bf16_t, 3><<<dim3(16, 32), blk, 0, stream>>>(y_kv, uv_t, Vt, M, 2048, 512);
  // rope + remaining packs
  rope64<<<(M * 32 + 255) / 256, blk, 0, stream>>>(kr, M);
  rope_qp<<<(32 * S_ * 32 + 255) / 256, blk, 0, stream>>>(Qp);
  pack_kr<<<(32 * S_ * 64 + 255) / 256, blk, 0, stream>>>(kr, Kp);
  // flash attention (pair-balanced, gload_lds-staged)
  flash_attn3<<<512, blk, 0, stream>>>(Qp, Kp, Vt, ao);
  // output projection
  gemm_bt<float, 0><<<dim3(16, 32), blk, 0, stream>>>(ao, o_t, out, M, 2048, 2048);
}